// Round 1
// baseline (161.478 us; speedup 1.0000x reference)
//
#include <hip/hip_runtime.h>

// out[b, o*8+n, h, w] = sum_k W[o,k] * x[b, n*32+k, h, w]
// B=32, C=512, H=W=56 (HW=3136), 8 windows (stride 32, width 64), W is 64x64.

#define HW    3136
#define NCH   512
#define CHW   (NCH * HW)

__global__ __launch_bounds__(448) void SKC_65841848648481_kernel(
    const float* __restrict__ x,
    const float* __restrict__ w,
    float* __restrict__ out)
{
    // LDS copy of weights, transposed: wl[k*64 + o] = w[o*64 + k]
    __shared__ float wl[64 * 64];
    const int tid = threadIdx.x;
    for (int i = tid; i < 64 * 64; i += 448) {
        const int o = i >> 6;
        const int k = i & 63;
        wl[(k << 6) + o] = w[i];
    }
    __syncthreads();

    const int hw = blockIdx.x * 448 + tid;   // 7 * 448 == 3136, no tail
    const int n  = blockIdx.y;               // window index 0..7
    const int b  = blockIdx.z;               // batch 0..31

    const float* xp = x + (size_t)b * CHW + (size_t)(n * 32) * HW + hw;

    float acc[64];
    #pragma unroll
    for (int o = 0; o < 64; ++o) acc[o] = 0.0f;

    #pragma unroll 2
    for (int k = 0; k < 64; ++k) {
        const float xv = xp[(size_t)k * HW];           // coalesced across lanes
        const float4* wr = (const float4*)(&wl[k << 6]); // uniform addr -> broadcast
        #pragma unroll
        for (int o4 = 0; o4 < 16; ++o4) {
            const float4 wv = wr[o4];
            acc[o4 * 4 + 0] = fmaf(wv.x, xv, acc[o4 * 4 + 0]);
            acc[o4 * 4 + 1] = fmaf(wv.y, xv, acc[o4 * 4 + 1]);
            acc[o4 * 4 + 2] = fmaf(wv.z, xv, acc[o4 * 4 + 2]);
            acc[o4 * 4 + 3] = fmaf(wv.w, xv, acc[o4 * 4 + 3]);
        }
    }

    // out channel c = o*8 + n
    float* op = out + (size_t)b * CHW + (size_t)n * HW + hw;
    #pragma unroll
    for (int o = 0; o < 64; ++o) {
        op[(size_t)(o * 8) * HW] = acc[o];
    }
}

extern "C" void kernel_launch(void* const* d_in, const int* in_sizes, int n_in,
                              void* d_out, int out_size, void* d_ws, size_t ws_size,
                              hipStream_t stream)
{
    const float* x  = (const float*)d_in[0];   // (32, 512, 56, 56) f32
    const float* w  = (const float*)d_in[1];   // (64, 64) f32
    float* out      = (float*)d_out;           // (32, 512, 56, 56) f32

    dim3 grid(7, 8, 32);   // hw-chunks x windows x batch
    dim3 block(448);
    hipLaunchKernelGGL(SKC_65841848648481_kernel, grid, block, 0, stream,
                       x, w, out);
}

// Round 2
// 133.004 us; speedup vs baseline: 1.2141x; 1.2141x over previous
//
#include <hip/hip_runtime.h>

// out[b, o*8+n, h, w] = sum_k W[o,k] * x[b, n*32+k, h, w]
// B=32, C=512, H=W=56 (HW=3136), 8 windows (stride 32, width 64), W is 64x64.
//
// Key idea: weights are wave-uniform per k -> keep them in SGPRs via uniform
// loads from a pre-transposed copy wT[k][o] in d_ws. Inner loop is pure
// v_fma_f32 (VGPR acc, SGPR weight, VGPR x). No LDS at all.

#define HW    3136
#define NCH   512
#define CHW   (NCH * HW)

__global__ __launch_bounds__(256) void SKC_transpose_w(
    const float* __restrict__ w, float* __restrict__ wT)
{
    const int i = blockIdx.x * 256 + threadIdx.x;   // 0..4095
    const int o = i >> 6;
    const int k = i & 63;
    wT[(k << 6) + o] = w[i];
}

__global__ __launch_bounds__(448) void SKC_65841848648481_kernel(
    const float* __restrict__ x,
    const float* __restrict__ wT,   // transposed weights: wT[k*64 + o]
    float* __restrict__ out)
{
    const int tid = threadIdx.x;
    const int hw  = blockIdx.x * 448 + tid;   // 7 * 448 == 3136, no tail
    const int n   = blockIdx.y;               // window 0..7
    const int b   = blockIdx.z;               // batch 0..31

    const float* xp = x + (size_t)b * CHW + (size_t)(n * 32) * HW + hw;

    float acc[64];
    #pragma unroll
    for (int o = 0; o < 64; ++o) acc[o] = 0.0f;

    // Prefetch-one-ahead on x. Overreading channel n*32+64 (<= 288 < 512) is
    // always in-bounds, so no tail condition needed.
    float xv = xp[0];
    for (int k = 0; k < 64; ++k) {
        const float xn = xp[(size_t)(k + 1) * HW];       // next-k prefetch
        const float* wr = wT + (k << 6);                 // wave-uniform addr -> s_load
        #pragma unroll
        for (int o = 0; o < 64; ++o) {
            acc[o] = fmaf(wr[o], xv, acc[o]);            // v_fma vD, sW, vX
        }
        xv = xn;
    }

    // out channel c = o*8 + n
    float* op = out + (size_t)b * CHW + (size_t)n * HW + hw;
    #pragma unroll
    for (int o = 0; o < 64; ++o) {
        op[(size_t)(o * 8) * HW] = acc[o];
    }
}

extern "C" void kernel_launch(void* const* d_in, const int* in_sizes, int n_in,
                              void* d_out, int out_size, void* d_ws, size_t ws_size,
                              hipStream_t stream)
{
    const float* x  = (const float*)d_in[0];   // (32, 512, 56, 56) f32
    const float* w  = (const float*)d_in[1];   // (64, 64) f32
    float* out      = (float*)d_out;           // (32, 512, 56, 56) f32
    float* wT       = (float*)d_ws;            // 4096 floats scratch

    hipLaunchKernelGGL(SKC_transpose_w, dim3(16), dim3(256), 0, stream, w, wT);

    dim3 grid(7, 8, 32);   // hw-chunks x windows x batch
    dim3 block(448);
    hipLaunchKernelGGL(SKC_65841848648481_kernel, grid, block, 0, stream,
                       x, wT, out);
}

// Round 3
// 91.557 us; speedup vs baseline: 1.7637x; 1.4527x over previous
//
#include <hip/hip_runtime.h>

// out[b, o*8+n, h, w] = sum_k W[o,k] * x[b, n*32+k, h, w]
// B=32, C=512, HW=3136, 8 windows (stride 32, width 64), W is 64x64 f32.
//
// Per (b,n): C[64 x 3136] = W[64x64] . X[64 x 3136]  -> bf16 MFMA 32x32x16.
// Per wave: one 32-pixel strip, full K=64, M=64 (2 M-tiles).
//   A-frag (W): lane l holds W[m*32 + (l&31)][s*16 + (l>>5)*8 + j], j=0..7
//   B-frag (X): lane l holds x[n*32 + s*16 + (l>>5)*8 + j][p0 + (l&31)]
//   C:          col = lane&31, row = (reg&3) + 8*(reg>>2) + 4*(lane>>5)  [m74/m101]
// All global accesses are whole aligned 128B lines (HW*4 % 128 == 0).

#define HW   3136
#define CHW  (512 * HW)

typedef float f32x16 __attribute__((ext_vector_type(16)));
typedef int   i32x4  __attribute__((ext_vector_type(4)));

__device__ __forceinline__ unsigned pk_bf16(float lo, float hi) {
    unsigned r;
    asm("v_cvt_pk_bf16_f32 %0, %1, %2" : "=v"(r) : "v"(lo), "v"(hi));
    return r;   // bits[15:0] = bf16(lo), bits[31:16] = bf16(hi)
}

__device__ __forceinline__ void mfma_32x32x16_bf16(f32x16& acc, i32x4 a, i32x4 b) {
    asm volatile("v_mfma_f32_32x32x16_bf16 %0, %1, %2, %0"
                 : "+v"(acc) : "v"(a), "v"(b));
}

__global__ __launch_bounds__(128) void SKC_65841848648481_kernel(
    const float* __restrict__ x,
    const float* __restrict__ w,
    float* __restrict__ out)
{
    const int lane = threadIdx.x & 63;
    const int wave = threadIdx.x >> 6;              // 0..1
    const int lc   = lane & 31;                     // tile col (pixel)
    const int lh   = lane >> 5;                     // k-half selector
    const int n    = blockIdx.y;                    // window 0..7
    const int b    = blockIdx.z;                    // batch 0..31
    const int p0   = (blockIdx.x * 2 + wave) * 32;  // strip base pixel (49*2*32 = 3136)

    // ---- W -> A fragments (register-resident for whole kernel) ----
    i32x4 afrag[2][4];
    #pragma unroll
    for (int m = 0; m < 2; ++m) {
        const float* wr = w + (m * 32 + lc) * 64;   // row o = m*32 + lc
        #pragma unroll
        for (int s = 0; s < 4; ++s) {
            const float4 w0 = *(const float4*)(wr + s * 16 + lh * 8);
            const float4 w1 = *(const float4*)(wr + s * 16 + lh * 8 + 4);
            i32x4 a;
            a.x = pk_bf16(w0.x, w0.y);
            a.y = pk_bf16(w0.z, w0.w);
            a.z = pk_bf16(w1.x, w1.y);
            a.w = pk_bf16(w1.z, w1.w);
            afrag[m][s] = a;
        }
    }

    // ---- X gather: xv[s][j] = x[ch = n*32 + s*16 + lh*8 + j][p0 + lc] ----
    // max channel = 7*32 + 63 = 287 < 512, always in-bounds.
    const float* xp = x + (size_t)b * CHW + (size_t)(n * 32 + lh * 8) * HW + p0 + lc;
    float xv[4][8];
    #pragma unroll
    for (int s = 0; s < 4; ++s) {
        #pragma unroll
        for (int j = 0; j < 8; ++j) {
            xv[s][j] = xp[(size_t)(s * 16 + j) * HW];   // 2x 128B lines per instr
        }
    }

    // ---- pack B fragments ----
    i32x4 bfrag[4];
    #pragma unroll
    for (int s = 0; s < 4; ++s) {
        i32x4 bq;
        bq.x = pk_bf16(xv[s][0], xv[s][1]);
        bq.y = pk_bf16(xv[s][2], xv[s][3]);
        bq.z = pk_bf16(xv[s][4], xv[s][5]);
        bq.w = pk_bf16(xv[s][6], xv[s][7]);
        bfrag[s] = bq;
    }

    // ---- MFMA: acc[m] += A[m][s] * B[s] over 4 K-steps ----
    f32x16 acc[2];
    #pragma unroll
    for (int m = 0; m < 2; ++m)
        #pragma unroll
        for (int r = 0; r < 16; ++r)
            acc[m][r] = 0.0f;

    #pragma unroll
    for (int s = 0; s < 4; ++s) {
        mfma_32x32x16_bf16(acc[0], afrag[0][s], bfrag[s]);
        mfma_32x32x16_bf16(acc[1], afrag[1][s], bfrag[s]);
    }

    // ---- store: out channel = (m*32 + row)*8 + n, pixel = p0 + lc ----
    float* op = out + (size_t)b * CHW + (size_t)n * HW + p0 + lc;
    #pragma unroll
    for (int m = 0; m < 2; ++m) {
        #pragma unroll
        for (int r = 0; r < 16; ++r) {
            const int row = (r & 3) + 8 * (r >> 2) + 4 * lh;   // verified C/D layout
            op[(size_t)((m * 32 + row) * 8) * HW] = acc[m][r]; // full 128B lines
        }
    }
}

extern "C" void kernel_launch(void* const* d_in, const int* in_sizes, int n_in,
                              void* d_out, int out_size, void* d_ws, size_t ws_size,
                              hipStream_t stream)
{
    const float* x  = (const float*)d_in[0];   // (32, 512, 56, 56) f32
    const float* w  = (const float*)d_in[1];   // (64, 64) f32
    float* out      = (float*)d_out;           // (32, 512, 56, 56) f32

    dim3 grid(49, 8, 32);   // 49 strip-pairs x 8 windows x 32 batches
    dim3 block(128);        // 2 waves, one 32-pixel strip each
    hipLaunchKernelGGL(SKC_65841848648481_kernel, grid, block, 0, stream,
                       x, w, out);
}

// Round 5
// 87.458 us; speedup vs baseline: 1.8463x; 1.0469x over previous
//
#include <hip/hip_runtime.h>

// out[b, o*8+n, h, w] = sum_k W[o,k] * x[b, n*32+k, h, w]
// B=32, C=512, HW=3136, 8 windows (stride 32, width 64), W is 64x64 f32.
//
// Per (b,n): C[64 x 3136] = W[64x64] . X[64 x 3136] via bf16 MFMA 32x32x16
// (builtin — compiler-managed hazards; round-4's inline-asm path suspected of
// silent MFMA hazard corruption and removed).
//
// Per wave: one 64-pixel strip as TWO interleaved 32-col tiles:
//   tile t (t=0,1), col c  <->  pixel p0 + 2*c + t
// Lane lc's float2 load at pixel p0+2*lc feeds tile0 (.x) and tile1 (.y);
// stores pair both tiles back into one float2. No cross-lane traffic, no LDS.
//
// Fragment mappings (end-to-end verified by the round-3 pass, absmax 0.0156):
//   A: lane l, elem j holds W[m*32 + (l&31)][s*16 + (l>>5)*8 + j]
//   B: lane l, elem j holds x[ch = n*32 + s*16 + (l>>5)*8 + j][pixel(col=l&31)]
//   C: col = lane&31, row = (reg&3) + 8*(reg>>2) + 4*(lane>>5)

#define HW   3136
#define CHW  (512 * HW)

typedef float  f32x16 __attribute__((ext_vector_type(16)));
typedef float  f32x2  __attribute__((ext_vector_type(2)));
typedef __bf16 bf16x8 __attribute__((ext_vector_type(8)));

__global__ __launch_bounds__(64, 2) void SKC_65841848648481_kernel(
    const float* __restrict__ x,
    const float* __restrict__ w,
    float* __restrict__ out)
{
    const int lane = threadIdx.x;
    const int lc   = lane & 31;
    const int lh   = lane >> 5;

    // Bijective XCD swizzle: 12544 work-ids, 12544 % 8 == 0, 1568 contiguous
    // ids per XCD -> window-overlap re-reads stay in that XCD's L2.
    int id = blockIdx.x;
    id = (id & 7) * 1568 + (id >> 3);
    const int strip = id % 49;              // 64-px strip within (b,n)
    const int n     = (id / 49) & 7;        // window 0..7
    const int b     = id / 392;             // batch 0..31
    const int p0    = strip * 64;

    // ---- W -> A fragments (register-resident; scalar bf16 casts) ----
    bf16x8 afrag[2][4];
    #pragma unroll
    for (int m = 0; m < 2; ++m) {
        const float* wr = w + (m * 32 + lc) * 64;
        #pragma unroll
        for (int s = 0; s < 4; ++s) {
            const float4 w0 = *(const float4*)(wr + s * 16 + lh * 8);
            const float4 w1 = *(const float4*)(wr + s * 16 + lh * 8 + 4);
            bf16x8 a;
            a[0] = (__bf16)w0.x; a[1] = (__bf16)w0.y;
            a[2] = (__bf16)w0.z; a[3] = (__bf16)w0.w;
            a[4] = (__bf16)w1.x; a[5] = (__bf16)w1.y;
            a[6] = (__bf16)w1.z; a[7] = (__bf16)w1.w;
            afrag[m][s] = a;
        }
    }

    // ---- X gather: float2 per (s,j) at pixels p0+2lc, p0+2lc+1 of channel
    //      ch = n*32 + s*16 + lh*8 + j  (max 287 < 512, in-bounds) ----
    const float* xp = x + (size_t)b * CHW + (size_t)(n * 32 + lh * 8) * HW + p0 + 2 * lc;
    f32x2 xv[4][8];
    #pragma unroll
    for (int s = 0; s < 4; ++s) {
        #pragma unroll
        for (int j = 0; j < 8; ++j) {
            xv[s][j] = *(const f32x2*)(xp + (size_t)(s * 16 + j) * HW);
        }
    }

    // ---- pack B fragments ----
    bf16x8 bfrag[2][4];
    #pragma unroll
    for (int s = 0; s < 4; ++s) {
        bf16x8 b0, b1;
        #pragma unroll
        for (int j = 0; j < 8; ++j) {
            b0[j] = (__bf16)xv[s][j].x;
            b1[j] = (__bf16)xv[s][j].y;
        }
        bfrag[0][s] = b0;
        bfrag[1][s] = b1;
    }

    // ---- MFMA: acc[t][m] += A[m][s] * B[t][s] ----
    f32x16 acc[2][2];
    #pragma unroll
    for (int t = 0; t < 2; ++t)
        #pragma unroll
        for (int m = 0; m < 2; ++m)
            #pragma unroll
            for (int r = 0; r < 16; ++r)
                acc[t][m][r] = 0.0f;

    #pragma unroll
    for (int s = 0; s < 4; ++s) {
        #pragma unroll
        for (int m = 0; m < 2; ++m) {
            acc[0][m] = __builtin_amdgcn_mfma_f32_32x32x16_bf16(
                afrag[m][s], bfrag[0][s], acc[0][m], 0, 0, 0);
            acc[1][m] = __builtin_amdgcn_mfma_f32_32x32x16_bf16(
                afrag[m][s], bfrag[1][s], acc[1][m], 0, 0, 0);
        }
    }

    // ---- store: channel (m*32+row)*8 + n, pixels p0+2lc (+1), plain f32x2 ----
    float* op = out + (size_t)b * CHW + (size_t)n * HW + p0 + 2 * lc;
    #pragma unroll
    for (int m = 0; m < 2; ++m) {
        #pragma unroll
        for (int r = 0; r < 16; ++r) {
            const int row = (r & 3) + 8 * (r >> 2) + 4 * lh;
            f32x2 v;
            v.x = acc[0][m][r];
            v.y = acc[1][m][r];
            *(f32x2*)(op + (size_t)((m * 32 + row) * 8) * HW) = v;
        }
    }
}

extern "C" void kernel_launch(void* const* d_in, const int* in_sizes, int n_in,
                              void* d_out, int out_size, void* d_ws, size_t ws_size,
                              hipStream_t stream)
{
    const float* x  = (const float*)d_in[0];   // (32, 512, 56, 56) f32
    const float* w  = (const float*)d_in[1];   // (64, 64) f32
    float* out      = (float*)d_out;           // (32, 512, 56, 56) f32

    dim3 grid(49 * 8 * 32);   // one wave per 64-px strip
    dim3 block(64);
    hipLaunchKernelGGL(SKC_65841848648481_kernel, grid, block, 0, stream,
                       x, w, out);
}